// Round 17
// baseline (221.615 us; speedup 1.0000x reference)
//
#include <hip/hip_runtime.h>
#include <math.h>

#define L2C 25
#define CH  128
#define NB  16
#define GLB 7
#define GLA 13
#define NG  91
#define GPAD 96
#define KPAD 32
#define HROWS 401   // 400 used rows (=16*25) + 1 pad row

typedef short bf16x8 __attribute__((ext_vector_type(8)));
typedef int   i32x4  __attribute__((ext_vector_type(4)));
typedef float f32x4  __attribute__((ext_vector_type(4)));
typedef unsigned uint2v __attribute__((ext_vector_type(2)));

union frag_u { i32x4 i; bf16x8 h; };

__device__ inline short f2bf(float f) {
  union { float f; unsigned u; } v; v.f = f;
  unsigned r = (v.u + 0x7FFFu + ((v.u >> 16) & 1u)) >> 16;
  return (short)r;
}
__device__ inline unsigned cvt_pk_bf16(float lo, float hi) {
  unsigned r; asm("v_cvt_pk_bf16_f32 %0, %1, %2" : "=v"(r) : "v"(lo), "v"(hi)); return r;
}

// ---------------- SH tables (bf16), built on device (R16: 5-iter Newton) ----------------
__global__ void build_tables_kernel(short* __restrict__ toT, short* __restrict__ frT) {
  const int g = threadIdx.x;
  if (g >= GPAD) return;
  const double PI = 3.14159265358979323846;
  double Y[L2C];
  double wg = 0.0;
  if (g < NG) {
    const int b = g / GLA;
    const int a = g % GLA;
    double xx = cos(PI * (b + 0.75) / (GLB + 0.5));
    double pp = 1.0;
    for (int it = 0; it < 5; ++it) {
      double p0 = 1.0, p1 = xx;
      for (int j = 2; j <= GLB; ++j) { double p2 = ((2.0*j-1.0)*xx*p1 - (j-1.0)*p0)/j; p0 = p1; p1 = p2; }
      pp = GLB * (xx*p1 - p0) / (xx*xx - 1.0);
      xx -= p1 / pp;
    }
    { double p0 = 1.0, p1 = xx;
      for (int j = 2; j <= GLB; ++j) { double p2 = ((2.0*j-1.0)*xx*p1 - (j-1.0)*p0)/j; p0 = p1; p1 = p2; }
      pp = GLB * (xx*p1 - p0) / (xx*xx - 1.0); }
    const double wb = 2.0 / ((1.0 - xx*xx) * pp * pp);
    const double ct = xx;
    const double sx = sqrt(fmax(0.0, 1.0 - ct*ct));
    double P[5][5];
    P[0][0] = 1.0;
    for (int m = 1; m <= 4; ++m) P[m][m] = -(2.0*m - 1.0) * sx * P[m-1][m-1];
    for (int m = 0; m <= 3; ++m) P[m+1][m] = (2.0*m + 1.0) * ct * P[m][m];
    for (int m = 0; m <= 4; ++m)
      for (int l = m + 2; l <= 4; ++l)
        P[l][m] = ((2.0*l-1.0)*ct*P[l-1][m] - (l+m-1.0)*P[l-2][m]) / (l - m);
    const double fact[9] = {1,1,2,6,24,120,720,5040,40320};
    const double phi = (2.0*PI/GLA) * a;
    for (int l = 0; l <= 4; ++l)
      for (int m = 0; m <= l; ++m) {
        double Nlm = sqrt((2.0*l+1.0)/(4.0*PI) * fact[l-m]/fact[l+m]);
        if (m == 0) Y[l*l + l] = Nlm * P[l][0];
        else {
          double base = sqrt(2.0) * Nlm * P[l][m];
          Y[l*l + l + m] = base * cos((double)m * phi);
          Y[l*l + l - m] = base * sin((double)m * phi);
        }
      }
    wg = wb * (2.0*PI/GLA);
  }
  for (int l = 0; l < KPAD; ++l) {
    float tv = (g < NG && l < L2C) ? (float)Y[l] : 0.f;
    toT[g*KPAD + l] = f2bf(tv);
  }
  {
    const int hi = g >> 4, r = g & 15;
    const int ksv = hi >> 1, pa = hi & 1;
    const int lqv = r >> 2,  pb = r & 3;
    const int kg = ksv*32 + lqv*8 + pa*4 + pb;
    for (int l = 0; l < KPAD; ++l)
      frT[l*GPAD + kg] = (g < NG && l < L2C) ? f2bf((float)(wg * Y[l])) : (short)0;
  }
}

__global__ void convert_w_kernel(const float* __restrict__ w1, const float* __restrict__ w2,
                                 short* __restrict__ wb1, short* __restrict__ wb2) {
  const int i = blockIdx.x * 256 + threadIdx.x;
  if (i < 5*CH*CH) { wb1[i] = f2bf(w1[i]); wb2[i] = f2bf(w2[i]); }
}

// ==== NB=16, 1024 threads (16 waves, 4/SIMD): slot-range split linears, node-split Gaunt ====
__global__ __launch_bounds__(1024, 4) void eqv3_fused16w(
    const float* __restrict__ x,
    const float* __restrict__ norm_w, const float* __restrict__ norm_b,
    const short* __restrict__ wb1, const float* __restrict__ b1,
    const float* __restrict__ w_tp,
    const short* __restrict__ wb2, const float* __restrict__ b2,
    const short* __restrict__ toT, const short* __restrict__ frT,
    float* __restrict__ out)
{
  __shared__ __align__(16) short u[65536];            // 131,072 B single buffer
  short (*hsh)[HROWS][8] = (short (*)[HROWS][8])u;    // view A: [16][401][8]
  short (*hg)[4][CH][8]  = (short (*)[4][CH][8])u;    // view B: [16][4][128][8]

  const int tid  = threadIdx.x;
  const int w    = tid >> 6;      // 16 waves
  const int kw   = w & 7;         // channel-column wave
  const int hw   = w >> 3;        // slot-half / node-half
  const int lane = tid & 63;
  const int l16  = lane & 15;
  const int lq   = lane >> 4;
  const long n0  = (long)blockIdx.x * NB;
  const int k    = kw*16 + l16;   // this wave's channel column

  constexpr int LDEG[L2C] = {0,1,1,1,2,2,2,2,2,3,3,3,3,3,3,3,4,4,4,4,4,4,4,4,4};

  // ---- LayerNorm: wave w owns node w (16 waves = 16 nodes) ----
  {
    const int node = w;
    const float4* x4 = (const float4*)(x + (n0 + node)*(long)(L2C*CH));
    float4 xv[13];
    float s0 = 0.f, s0q = 0.f, sq = 0.f;
    #pragma unroll
    for (int it = 0; it < 13; ++it) {
      const int j = it*64 + lane;
      if (j < 800) {
        xv[it] = x4[j];
        const float t = xv[it].x*xv[it].x + xv[it].y*xv[it].y + xv[it].z*xv[it].z + xv[it].w*xv[it].w;
        if (j < 32) { s0 += xv[it].x + xv[it].y + xv[it].z + xv[it].w; s0q += t; }
        else        sq += t;
      }
    }
    #pragma unroll
    for (int o = 1; o < 64; o <<= 1) {
      s0  += __shfl_xor(s0,  o, 64);
      s0q += __shfl_xor(s0q, o, 64);
      sq  += __shfl_xor(sq,  o, 64);
    }
    const float mean0 = s0 * (1.f/CH);
    const float var   = (sq + s0q - CH*mean0*mean0) * (1.f/(L2C*CH));
    const float rstd  = rsqrtf(var + 1e-5f);
    #pragma unroll
    for (int it = 0; it < 13; ++it) {
      const int j = it*64 + lane;
      if (j < 800) {
        const int s = j >> 5;
        const int d = (int)sqrtf((float)s + 0.5f);  // exact floor-sqrt for s<25
        const int row = 16*s + node;
        const int c32 = j & 31;
        const int c0  = c32 * 4;
        const float4 nw4 = ((const float4*)norm_w)[d*32 + c32];
        float a0 = xv[it].x, a1 = xv[it].y, a2 = xv[it].z, a3 = xv[it].w;
        if (s == 0) {
          const float4 nb4 = ((const float4*)norm_b)[c32];
          a0 = (a0 - mean0)*rstd*nw4.x + nb4.x;
          a1 = (a1 - mean0)*rstd*nw4.y + nb4.y;
          a2 = (a2 - mean0)*rstd*nw4.z + nb4.z;
          a3 = (a3 - mean0)*rstd*nw4.w + nb4.w;
        } else {
          a0 *= rstd*nw4.x; a1 *= rstd*nw4.y; a2 *= rstd*nw4.z; a3 *= rstd*nw4.w;
        }
        uint2v pk; pk[0] = cvt_pk_bf16(a0, a1); pk[1] = cvt_pk_bf16(a2, a3);
        *(uint2v*)&hsh[c0 >> 3][row][c0 & 7] = pk;
      }
    }
  }
  __syncthreads();   // (1) LN staged (all 400 rows)

  // ---- linear1: slot-range split (hw=0: s0..12, hw=1: s13..24) ----
  unsigned pk1[13][2];
  const float b1k = b1[k];
#define L1SEG(D, S0, S1, SB) { \
    frag_u Bf[4]; \
    _Pragma("unroll") for (int ks = 0; ks < 4; ++ks) \
      Bf[ks].i = *(const i32x4*)(wb1 + (((D)*CH + k)*CH + ks*32 + lq*8)); \
    _Pragma("unroll") for (int s = (S0); s < (S1); ++s) { \
      f32x4 acc = {0.f,0.f,0.f,0.f}; \
      _Pragma("unroll") for (int ks = 0; ks < 4; ++ks) { \
        const bf16x8 a = *(const bf16x8*)&hsh[ks*4 + lq][16*s + l16][0]; \
        acc = __builtin_amdgcn_mfma_f32_16x16x32_bf16(a, Bf[ks].h, acc, 0, 0, 0); } \
      const float bb = (s == 0) ? b1k : 0.f; \
      pk1[s - (SB)][0] = cvt_pk_bf16(acc[0] + bb, acc[1] + bb); \
      pk1[s - (SB)][1] = cvt_pk_bf16(acc[2] + bb, acc[3] + bb); } }
  if (hw == 0) {
    L1SEG(0, 0, 1, 0); L1SEG(1, 1, 4, 0); L1SEG(2, 4, 9, 0); L1SEG(3, 9, 13, 0);
  } else {
    L1SEG(3, 13, 16, 13); L1SEG(4, 16, 25, 13);
  }
#undef L1SEG
  __syncthreads();   // (2) ALL lin1 reads complete; buffer reusable in hg view

  // ---- hoisted Gaunt table loads (hide under hg writes) ----
  frag_u Ato[6];
  #pragma unroll
  for (int gt = 0; gt < 6; ++gt)
    Ato[gt].i = *(const i32x4*)(toT + (gt*16 + l16)*KPAD + lq*8);
  frag_u Afr[2][3];
  #pragma unroll
  for (int mt = 0; mt < 2; ++mt)
    #pragma unroll
    for (int ks = 0; ks < 3; ++ks)
      Afr[mt][ks].i = *(const i32x4*)(frT + (mt*16 + l16)*GPAD + ks*32 + lq*8);
  float wtp[2][4]; int hrowb[2][4];
  #pragma unroll
  for (int mt = 0; mt < 2; ++mt)
    #pragma unroll
    for (int i = 0; i < 4; ++i) {
      const int l = mt*16 + lq*4 + i;
      if (l < L2C) {
        wtp[mt][i]   = w_tp[LDEG[l]*CH + k];
        hrowb[mt][i] = 16*l;
      } else { wtp[mt][i] = 0.f; hrowb[mt][i] = -1; }
    }

  // ---- write lin1 output (hg view); hw halves share column k -> barrier after ----
  {
    if (hw == 1) {
      const i32x4 z = {0,0,0,0};
      #pragma unroll
      for (int j = 0; j < 4; ++j)
        *(i32x4*)&hg[lq*4 + j][3][k][0] = z;   // zero slots 24..31 (s=24 rewritten below)
    }
    const int nb = lq*4;
    if (hw == 0) {
      #pragma unroll
      for (int s = 0; s < 13; ++s) {
        hg[nb+0][s >> 3][k][s & 7] = (short)(pk1[s][0] & 0xFFFFu);
        hg[nb+1][s >> 3][k][s & 7] = (short)(pk1[s][0] >> 16);
        hg[nb+2][s >> 3][k][s & 7] = (short)(pk1[s][1] & 0xFFFFu);
        hg[nb+3][s >> 3][k][s & 7] = (short)(pk1[s][1] >> 16);
      }
    } else {
      #pragma unroll
      for (int s = 13; s < 25; ++s) {
        hg[nb+0][s >> 3][k][s & 7] = (short)(pk1[s-13][0] & 0xFFFFu);
        hg[nb+1][s >> 3][k][s & 7] = (short)(pk1[s-13][0] >> 16);
        hg[nb+2][s >> 3][k][s & 7] = (short)(pk1[s-13][1] & 0xFFFFu);
        hg[nb+3][s >> 3][k][s & 7] = (short)(pk1[s-13][1] >> 16);
      }
    }
  }
  __syncthreads();   // (3) hg complete (cross-wave columns)

  // ---- Bh prefetch: this wave's 8 nodes ----
  frag_u Bh[8];
  #pragma unroll
  for (int j = 0; j < 8; ++j)
    Bh[j].i = *(const i32x4*)&hg[hw*8 + j][lq][k][0];
  __syncthreads();   // (4) all hg reads done; Gaunt may write buffer in hsh view

  // ---- Gaunt: 8 nodes per wave; register from-grid handoff (R8) ----
  {
    #pragma unroll
    for (int j = 0; j < 8; ++j) {
      const int n = hw*8 + j;
      unsigned p[6][2];
      #pragma unroll
      for (int gt = 0; gt < 6; ++gt) {
        f32x4 acc = {0.f,0.f,0.f,0.f};
        acc = __builtin_amdgcn_mfma_f32_16x16x32_bf16(Ato[gt].h, Bh[j].h, acc, 0, 0, 0);
        p[gt][0] = cvt_pk_bf16(acc[0]*acc[0], acc[1]*acc[1]);
        p[gt][1] = cvt_pk_bf16(acc[2]*acc[2], acc[3]*acc[3]);
      }
      f32x4 acc2[2] = {{0.f,0.f,0.f,0.f},{0.f,0.f,0.f,0.f}};
      #pragma unroll
      for (int ks = 0; ks < 3; ++ks) {
        frag_u Bg;
        Bg.i[0] = (int)p[2*ks][0];
        Bg.i[1] = (int)p[2*ks][1];
        Bg.i[2] = (int)p[2*ks+1][0];
        Bg.i[3] = (int)p[2*ks+1][1];
        acc2[0] = __builtin_amdgcn_mfma_f32_16x16x32_bf16(Afr[0][ks].h, Bg.h, acc2[0], 0, 0, 0);
        acc2[1] = __builtin_amdgcn_mfma_f32_16x16x32_bf16(Afr[1][ks].h, Bg.h, acc2[1], 0, 0, 0);
      }
      #pragma unroll
      for (int mt = 0; mt < 2; ++mt)
        #pragma unroll
        for (int i = 0; i < 4; ++i)
          if (hrowb[mt][i] >= 0)
            hsh[k >> 3][hrowb[mt][i] + n][k & 7] = f2bf(acc2[mt][i] * wtp[mt][i]);
    }
  }
  __syncthreads();   // (5) Gaunt output staged (hsh view)

  // ---- linear2: slot-range split + bias(l=0) + residual -> direct global store ----
  {
    const float b2k = b2[k];
#define L2SEG(D, S0, S1) { \
    frag_u Bf[4]; \
    _Pragma("unroll") for (int ks = 0; ks < 4; ++ks) \
      Bf[ks].i = *(const i32x4*)(wb2 + (((D)*CH + k)*CH + ks*32 + lq*8)); \
    _Pragma("unroll") for (int s = (S0); s < (S1); ++s) { \
      f32x4 acc = {0.f,0.f,0.f,0.f}; \
      _Pragma("unroll") for (int ks = 0; ks < 4; ++ks) { \
        const bf16x8 a = *(const bf16x8*)&hsh[ks*4 + lq][16*s + l16][0]; \
        acc = __builtin_amdgcn_mfma_f32_16x16x32_bf16(a, Bf[ks].h, acc, 0, 0, 0); } \
      const float bb = (s == 0) ? b2k : 0.f; \
      _Pragma("unroll") for (int i = 0; i < 4; ++i) { \
        const int node = lq*4 + i; \
        const long base = (n0 + node)*(long)(L2C*CH) + s*CH + k; \
        out[base] = acc[i] + bb + x[base]; } } }
    if (hw == 0) {
      L2SEG(0, 0, 1); L2SEG(1, 1, 4); L2SEG(2, 4, 9); L2SEG(3, 9, 13);
    } else {
      L2SEG(3, 13, 16); L2SEG(4, 16, 25);
    }
#undef L2SEG
  }
}

// ---------------- launch ----------------
extern "C" void kernel_launch(void* const* d_in, const int* in_sizes, int n_in,
                              void* d_out, int out_size, void* d_ws, size_t ws_size,
                              hipStream_t stream) {
  const float* x      = (const float*)d_in[0];
  // d_in[1] = batch (unused)
  const float* norm_w = (const float*)d_in[2];
  const float* norm_b = (const float*)d_in[3];
  const float* w1     = (const float*)d_in[4];
  const float* b1     = (const float*)d_in[5];
  const float* w_tp   = (const float*)d_in[6];
  const float* w2     = (const float*)d_in[7];
  const float* b2     = (const float*)d_in[8];
  float* out = (float*)d_out;

  const int N = in_sizes[0] / (L2C*CH);   // 6000

  short* wsS = (short*)d_ws;              // ~340 KB
  short* toT = wsS;                       // [96][32]
  short* frT = toT + GPAD*KPAD;           // [32][96]
  short* wb1 = frT + KPAD*GPAD;           // [5][128][128]
  short* wb2 = wb1 + 5*CH*CH;

  build_tables_kernel<<<1, 128, 0, stream>>>(toT, frT);
  convert_w_kernel<<<(5*CH*CH + 255)/256, 256, 0, stream>>>(w1, w2, wb1, wb2);
  eqv3_fused16w<<<N/NB, 1024, 0, stream>>>(x, norm_w, norm_b, wb1, b1, w_tp, wb2, b2, toT, frT, out);
}

// Round 18
// 220.924 us; speedup vs baseline: 1.0031x; 1.0031x over previous
//
#include <hip/hip_runtime.h>
#include <math.h>

#define L2C 25
#define CH  128
#define NB  16
#define GLB 7
#define GLA 13
#define NG  91
#define GPAD 96
#define KPAD 32
#define HROWS 401   // 400 used rows (=16*25) + 1 pad row

typedef short bf16x8 __attribute__((ext_vector_type(8)));
typedef int   i32x4  __attribute__((ext_vector_type(4)));
typedef float f32x4  __attribute__((ext_vector_type(4)));
typedef unsigned uint2v __attribute__((ext_vector_type(2)));

union frag_u { i32x4 i; bf16x8 h; };

__device__ inline short f2bf(float f) {
  union { float f; unsigned u; } v; v.f = f;
  unsigned r = (v.u + 0x7FFFu + ((v.u >> 16) & 1u)) >> 16;
  return (short)r;
}
__device__ inline unsigned cvt_pk_bf16(float lo, float hi) {
  unsigned r; asm("v_cvt_pk_bf16_f32 %0, %1, %2" : "=v"(r) : "v"(lo), "v"(hi)); return r;
}

// ---------------- SH tables (bf16), built on device (R16: 5-iter Newton) ----------------
__global__ void build_tables_kernel(short* __restrict__ toT, short* __restrict__ frT) {
  const int g = threadIdx.x;
  if (g >= GPAD) return;
  const double PI = 3.14159265358979323846;
  double Y[L2C];
  double wg = 0.0;
  if (g < NG) {
    const int b = g / GLA;
    const int a = g % GLA;
    double xx = cos(PI * (b + 0.75) / (GLB + 0.5));
    double pp = 1.0;
    for (int it = 0; it < 5; ++it) {
      double p0 = 1.0, p1 = xx;
      for (int j = 2; j <= GLB; ++j) { double p2 = ((2.0*j-1.0)*xx*p1 - (j-1.0)*p0)/j; p0 = p1; p1 = p2; }
      pp = GLB * (xx*p1 - p0) / (xx*xx - 1.0);
      xx -= p1 / pp;
    }
    { double p0 = 1.0, p1 = xx;
      for (int j = 2; j <= GLB; ++j) { double p2 = ((2.0*j-1.0)*xx*p1 - (j-1.0)*p0)/j; p0 = p1; p1 = p2; }
      pp = GLB * (xx*p1 - p0) / (xx*xx - 1.0); }
    const double wb = 2.0 / ((1.0 - xx*xx) * pp * pp);
    const double ct = xx;
    const double sx = sqrt(fmax(0.0, 1.0 - ct*ct));
    double P[5][5];
    P[0][0] = 1.0;
    for (int m = 1; m <= 4; ++m) P[m][m] = -(2.0*m - 1.0) * sx * P[m-1][m-1];
    for (int m = 0; m <= 3; ++m) P[m+1][m] = (2.0*m + 1.0) * ct * P[m][m];
    for (int m = 0; m <= 4; ++m)
      for (int l = m + 2; l <= 4; ++l)
        P[l][m] = ((2.0*l-1.0)*ct*P[l-1][m] - (l+m-1.0)*P[l-2][m]) / (l - m);
    const double fact[9] = {1,1,2,6,24,120,720,5040,40320};
    const double phi = (2.0*PI/GLA) * a;
    for (int l = 0; l <= 4; ++l)
      for (int m = 0; m <= l; ++m) {
        double Nlm = sqrt((2.0*l+1.0)/(4.0*PI) * fact[l-m]/fact[l+m]);
        if (m == 0) Y[l*l + l] = Nlm * P[l][0];
        else {
          double base = sqrt(2.0) * Nlm * P[l][m];
          Y[l*l + l + m] = base * cos((double)m * phi);
          Y[l*l + l - m] = base * sin((double)m * phi);
        }
      }
    wg = wb * (2.0*PI/GLA);
  }
  for (int l = 0; l < KPAD; ++l) {
    float tv = (g < NG && l < L2C) ? (float)Y[l] : 0.f;
    toT[g*KPAD + l] = f2bf(tv);
  }
  {
    const int hi = g >> 4, r = g & 15;
    const int ksv = hi >> 1, pa = hi & 1;
    const int lqv = r >> 2,  pb = r & 3;
    const int kg = ksv*32 + lqv*8 + pa*4 + pb;
    for (int l = 0; l < KPAD; ++l)
      frT[l*GPAD + kg] = (g < NG && l < L2C) ? f2bf((float)(wg * Y[l])) : (short)0;
  }
}

__global__ void convert_w_kernel(const float* __restrict__ w1, const float* __restrict__ w2,
                                 short* __restrict__ wb1, short* __restrict__ wb2) {
  const int i = blockIdx.x * 256 + threadIdx.x;
  if (i < 5*CH*CH) { wb1[i] = f2bf(w1[i]); wb2[i] = f2bf(w2[i]); }
}

// ==== NB=16, 1024 threads (16 waves, 4/SIMD, 1 block/CU -> 128 VGPR budget) ====
__global__ __launch_bounds__(1024, 1) void eqv3_fused16w(
    const float* __restrict__ x,
    const float* __restrict__ norm_w, const float* __restrict__ norm_b,
    const short* __restrict__ wb1, const float* __restrict__ b1,
    const float* __restrict__ w_tp,
    const short* __restrict__ wb2, const float* __restrict__ b2,
    const short* __restrict__ toT, const short* __restrict__ frT,
    float* __restrict__ out)
{
  __shared__ __align__(16) short u[65536];            // 131,072 B single buffer
  short (*hsh)[HROWS][8] = (short (*)[HROWS][8])u;    // view A: [16][401][8]
  short (*hg)[4][CH][8]  = (short (*)[4][CH][8])u;    // view B: [16][4][128][8]

  const int tid  = threadIdx.x;
  const int w    = tid >> 6;      // 16 waves
  const int kw   = w & 7;         // channel-column wave
  const int hw   = w >> 3;        // slot-half / node-half
  const int lane = tid & 63;
  const int l16  = lane & 15;
  const int lq   = lane >> 4;
  const long n0  = (long)blockIdx.x * NB;
  const int k    = kw*16 + l16;   // this wave's channel column

  constexpr int LDEG[L2C] = {0,1,1,1,2,2,2,2,2,3,3,3,3,3,3,3,4,4,4,4,4,4,4,4,4};

  // ---- LayerNorm: wave w owns node w (16 waves = 16 nodes) ----
  {
    const int node = w;
    const float4* x4 = (const float4*)(x + (n0 + node)*(long)(L2C*CH));
    float4 xv[13];
    float s0 = 0.f, s0q = 0.f, sq = 0.f;
    #pragma unroll
    for (int it = 0; it < 13; ++it) {
      const int j = it*64 + lane;
      if (j < 800) {
        xv[it] = x4[j];
        const float t = xv[it].x*xv[it].x + xv[it].y*xv[it].y + xv[it].z*xv[it].z + xv[it].w*xv[it].w;
        if (j < 32) { s0 += xv[it].x + xv[it].y + xv[it].z + xv[it].w; s0q += t; }
        else        sq += t;
      }
    }
    #pragma unroll
    for (int o = 1; o < 64; o <<= 1) {
      s0  += __shfl_xor(s0,  o, 64);
      s0q += __shfl_xor(s0q, o, 64);
      sq  += __shfl_xor(sq,  o, 64);
    }
    const float mean0 = s0 * (1.f/CH);
    const float var   = (sq + s0q - CH*mean0*mean0) * (1.f/(L2C*CH));
    const float rstd  = rsqrtf(var + 1e-5f);
    #pragma unroll
    for (int it = 0; it < 13; ++it) {
      const int j = it*64 + lane;
      if (j < 800) {
        const int s = j >> 5;
        const int d = (int)sqrtf((float)s + 0.5f);  // exact floor-sqrt for s<25
        const int row = 16*s + node;
        const int c32 = j & 31;
        const int c0  = c32 * 4;
        const float4 nw4 = ((const float4*)norm_w)[d*32 + c32];
        float a0 = xv[it].x, a1 = xv[it].y, a2 = xv[it].z, a3 = xv[it].w;
        if (s == 0) {
          const float4 nb4 = ((const float4*)norm_b)[c32];
          a0 = (a0 - mean0)*rstd*nw4.x + nb4.x;
          a1 = (a1 - mean0)*rstd*nw4.y + nb4.y;
          a2 = (a2 - mean0)*rstd*nw4.z + nb4.z;
          a3 = (a3 - mean0)*rstd*nw4.w + nb4.w;
        } else {
          a0 *= rstd*nw4.x; a1 *= rstd*nw4.y; a2 *= rstd*nw4.z; a3 *= rstd*nw4.w;
        }
        uint2v pk; pk[0] = cvt_pk_bf16(a0, a1); pk[1] = cvt_pk_bf16(a2, a3);
        *(uint2v*)&hsh[c0 >> 3][row][c0 & 7] = pk;
      }
    }
  }
  __syncthreads();   // (1) LN staged (all 400 rows)

  // ---- linear1: slot-range split (hw=0: s0..12, hw=1: s13..24) ----
  unsigned pk1[13][2];
  const float b1k = b1[k];
#define L1SEG(D, S0, S1, SB) { \
    frag_u Bf[4]; \
    _Pragma("unroll") for (int ks = 0; ks < 4; ++ks) \
      Bf[ks].i = *(const i32x4*)(wb1 + (((D)*CH + k)*CH + ks*32 + lq*8)); \
    _Pragma("unroll") for (int s = (S0); s < (S1); ++s) { \
      f32x4 acc = {0.f,0.f,0.f,0.f}; \
      _Pragma("unroll") for (int ks = 0; ks < 4; ++ks) { \
        const bf16x8 a = *(const bf16x8*)&hsh[ks*4 + lq][16*s + l16][0]; \
        acc = __builtin_amdgcn_mfma_f32_16x16x32_bf16(a, Bf[ks].h, acc, 0, 0, 0); } \
      const float bb = (s == 0) ? b1k : 0.f; \
      pk1[s - (SB)][0] = cvt_pk_bf16(acc[0] + bb, acc[1] + bb); \
      pk1[s - (SB)][1] = cvt_pk_bf16(acc[2] + bb, acc[3] + bb); } }
  if (hw == 0) {
    L1SEG(0, 0, 1, 0); L1SEG(1, 1, 4, 0); L1SEG(2, 4, 9, 0); L1SEG(3, 9, 13, 0);
  } else {
    L1SEG(3, 13, 16, 13); L1SEG(4, 16, 25, 13);
  }
#undef L1SEG
  __syncthreads();   // (2) ALL lin1 reads complete; buffer reusable in hg view

  // ---- hoisted Gaunt table loads (hide under hg writes) ----
  frag_u Ato[6];
  #pragma unroll
  for (int gt = 0; gt < 6; ++gt)
    Ato[gt].i = *(const i32x4*)(toT + (gt*16 + l16)*KPAD + lq*8);
  frag_u Afr[2][3];
  #pragma unroll
  for (int mt = 0; mt < 2; ++mt)
    #pragma unroll
    for (int ks = 0; ks < 3; ++ks)
      Afr[mt][ks].i = *(const i32x4*)(frT + (mt*16 + l16)*GPAD + ks*32 + lq*8);
  float wtp[2][4]; int hrowb[2][4];
  #pragma unroll
  for (int mt = 0; mt < 2; ++mt)
    #pragma unroll
    for (int i = 0; i < 4; ++i) {
      const int l = mt*16 + lq*4 + i;
      if (l < L2C) {
        wtp[mt][i]   = w_tp[LDEG[l]*CH + k];
        hrowb[mt][i] = 16*l;
      } else { wtp[mt][i] = 0.f; hrowb[mt][i] = -1; }
    }

  // ---- write lin1 output (hg view); hw halves share column k -> barrier after ----
  {
    if (hw == 1) {
      const i32x4 z = {0,0,0,0};
      #pragma unroll
      for (int j = 0; j < 4; ++j)
        *(i32x4*)&hg[lq*4 + j][3][k][0] = z;   // zero slots 24..31 (s=24 rewritten below)
    }
    const int nb = lq*4;
    if (hw == 0) {
      #pragma unroll
      for (int s = 0; s < 13; ++s) {
        hg[nb+0][s >> 3][k][s & 7] = (short)(pk1[s][0] & 0xFFFFu);
        hg[nb+1][s >> 3][k][s & 7] = (short)(pk1[s][0] >> 16);
        hg[nb+2][s >> 3][k][s & 7] = (short)(pk1[s][1] & 0xFFFFu);
        hg[nb+3][s >> 3][k][s & 7] = (short)(pk1[s][1] >> 16);
      }
    } else {
      #pragma unroll
      for (int s = 13; s < 25; ++s) {
        hg[nb+0][s >> 3][k][s & 7] = (short)(pk1[s-13][0] & 0xFFFFu);
        hg[nb+1][s >> 3][k][s & 7] = (short)(pk1[s-13][0] >> 16);
        hg[nb+2][s >> 3][k][s & 7] = (short)(pk1[s-13][1] & 0xFFFFu);
        hg[nb+3][s >> 3][k][s & 7] = (short)(pk1[s-13][1] >> 16);
      }
    }
  }
  __syncthreads();   // (3) hg complete (cross-wave columns)

  // ---- Bh prefetch: this wave's 8 nodes ----
  frag_u Bh[8];
  #pragma unroll
  for (int j = 0; j < 8; ++j)
    Bh[j].i = *(const i32x4*)&hg[hw*8 + j][lq][k][0];
  __syncthreads();   // (4) all hg reads done; Gaunt may write buffer in hsh view

  // ---- Gaunt: 8 nodes per wave; register from-grid handoff (R8) ----
  {
    #pragma unroll
    for (int j = 0; j < 8; ++j) {
      const int n = hw*8 + j;
      unsigned p[6][2];
      #pragma unroll
      for (int gt = 0; gt < 6; ++gt) {
        f32x4 acc = {0.f,0.f,0.f,0.f};
        acc = __builtin_amdgcn_mfma_f32_16x16x32_bf16(Ato[gt].h, Bh[j].h, acc, 0, 0, 0);
        p[gt][0] = cvt_pk_bf16(acc[0]*acc[0], acc[1]*acc[1]);
        p[gt][1] = cvt_pk_bf16(acc[2]*acc[2], acc[3]*acc[3]);
      }
      f32x4 acc2[2] = {{0.f,0.f,0.f,0.f},{0.f,0.f,0.f,0.f}};
      #pragma unroll
      for (int ks = 0; ks < 3; ++ks) {
        frag_u Bg;
        Bg.i[0] = (int)p[2*ks][0];
        Bg.i[1] = (int)p[2*ks][1];
        Bg.i[2] = (int)p[2*ks+1][0];
        Bg.i[3] = (int)p[2*ks+1][1];
        acc2[0] = __builtin_amdgcn_mfma_f32_16x16x32_bf16(Afr[0][ks].h, Bg.h, acc2[0], 0, 0, 0);
        acc2[1] = __builtin_amdgcn_mfma_f32_16x16x32_bf16(Afr[1][ks].h, Bg.h, acc2[1], 0, 0, 0);
      }
      #pragma unroll
      for (int mt = 0; mt < 2; ++mt)
        #pragma unroll
        for (int i = 0; i < 4; ++i)
          if (hrowb[mt][i] >= 0)
            hsh[k >> 3][hrowb[mt][i] + n][k & 7] = f2bf(acc2[mt][i] * wtp[mt][i]);
    }
  }
  __syncthreads();   // (5) Gaunt output staged (hsh view)

  // ---- linear2: slot-range split + bias(l=0) + residual -> direct global store ----
  {
    const float b2k = b2[k];
#define L2SEG(D, S0, S1) { \
    frag_u Bf[4]; \
    _Pragma("unroll") for (int ks = 0; ks < 4; ++ks) \
      Bf[ks].i = *(const i32x4*)(wb2 + (((D)*CH + k)*CH + ks*32 + lq*8)); \
    _Pragma("unroll") for (int s = (S0); s < (S1); ++s) { \
      f32x4 acc = {0.f,0.f,0.f,0.f}; \
      _Pragma("unroll") for (int ks = 0; ks < 4; ++ks) { \
        const bf16x8 a = *(const bf16x8*)&hsh[ks*4 + lq][16*s + l16][0]; \
        acc = __builtin_amdgcn_mfma_f32_16x16x32_bf16(a, Bf[ks].h, acc, 0, 0, 0); } \
      const float bb = (s == 0) ? b2k : 0.f; \
      _Pragma("unroll") for (int i = 0; i < 4; ++i) { \
        const int node = lq*4 + i; \
        const long base = (n0 + node)*(long)(L2C*CH) + s*CH + k; \
        out[base] = acc[i] + bb + x[base]; } } }
    if (hw == 0) {
      L2SEG(0, 0, 1); L2SEG(1, 1, 4); L2SEG(2, 4, 9); L2SEG(3, 9, 13);
    } else {
      L2SEG(3, 13, 16); L2SEG(4, 16, 25);
    }
#undef L2SEG
  }
}

// ---------------- launch ----------------
extern "C" void kernel_launch(void* const* d_in, const int* in_sizes, int n_in,
                              void* d_out, int out_size, void* d_ws, size_t ws_size,
                              hipStream_t stream) {
  const float* x      = (const float*)d_in[0];
  // d_in[1] = batch (unused)
  const float* norm_w = (const float*)d_in[2];
  const float* norm_b = (const float*)d_in[3];
  const float* w1     = (const float*)d_in[4];
  const float* b1     = (const float*)d_in[5];
  const float* w_tp   = (const float*)d_in[6];
  const float* w2     = (const float*)d_in[7];
  const float* b2     = (const float*)d_in[8];
  float* out = (float*)d_out;

  const int N = in_sizes[0] / (L2C*CH);   // 6000

  short* wsS = (short*)d_ws;              // ~340 KB
  short* toT = wsS;                       // [96][32]
  short* frT = toT + GPAD*KPAD;           // [32][96]
  short* wb1 = frT + KPAD*GPAD;           // [5][128][128]
  short* wb2 = wb1 + 5*CH*CH;

  build_tables_kernel<<<1, 128, 0, stream>>>(toT, frT);
  convert_w_kernel<<<(5*CH*CH + 255)/256, 256, 0, stream>>>(w1, w2, wb1, wb2);
  eqv3_fused16w<<<N/NB, 1024, 0, stream>>>(x, norm_w, norm_b, wb1, b1, w_tp, wb2, b2, toT, frT, out);
}